// Round 10
// baseline (287.397 us; speedup 1.0000x reference)
//
#include <hip/hip_runtime.h>
#include <hip/hip_bf16.h>
#include <cstdint>

// BiasedMHA bf16-MFMA pipeline: B=4, N=1024, FEAT=512, H=8, HD=64.
// detect mask -> canon (i32->u8, usually no-op) -> convert -> QKV GEMM
// (writes Q rows + fragment-major KF/VF with PV k-permutation baked) ->
// fused attention (swapped-QK^T in-register softmax, split-j x4 for
// 4 blocks/CU, defer-max) -> combine partials -> out-proj GEMM.

namespace {

typedef short bf16x8 __attribute__((ext_vector_type(8)));
typedef float f32x4 __attribute__((ext_vector_type(4)));
using u16 = unsigned short;
using u8 = unsigned char;

__device__ __forceinline__ u16 f2bf(float f) {
  union { float f; uint32_t i; } v;
  v.f = f;
  uint32_t r = v.i + 0x7fffu + ((v.i >> 16) & 1u);
  return (u16)(r >> 16);
}

__device__ __forceinline__ void gload_lds16(const void* g, void* l) {
  __builtin_amdgcn_global_load_lds(
      (__attribute__((address_space(1))) void*)g,
      (__attribute__((address_space(3))) void*)l, 16, 0, 0);
}
__device__ __forceinline__ void gload_lds4(const void* g, void* l) {
  __builtin_amdgcn_global_load_lds(
      (__attribute__((address_space(1))) void*)g,
      (__attribute__((address_space(3))) void*)l, 4, 0, 0);
}

// ---------------------------------------------------------------- mask dtype
__global__ void detect_mask_kernel(const unsigned char* __restrict__ m,
                                   int* __restrict__ flag) {
  __shared__ int red[256];
  int local = 0;
  for (int i = threadIdx.x; i < 65536; i += 256) local += (m[i] != 0) ? 1 : 0;
  red[threadIdx.x] = local;
  __syncthreads();
  for (int s = 128; s > 0; s >>= 1) {
    if ((int)threadIdx.x < s) red[threadIdx.x] += red[threadIdx.x + s];
    __syncthreads();
  }
  if (threadIdx.x == 0) *flag = (red[0] > 4915) ? 1 : 0;  // 7.5% threshold
}

__global__ __launch_bounds__(256) void canon_mask(const int* __restrict__ m32,
                                                  const int* __restrict__ flag,
                                                  u8* __restrict__ out) {
  if (*flag != 0) return;
  const size_t t = (size_t)blockIdx.x * 256 + threadIdx.x;
  const int4* src = (const int4*)m32 + t * 8;
  uchar4 ob[8];
#pragma unroll
  for (int q = 0; q < 8; ++q) {
    const int4 v = src[q];
    ob[q] = make_uchar4(v.x != 0, v.y != 0, v.z != 0, v.w != 0);
  }
  *(uint4*)(out + t * 32) = *(const uint4*)&ob[0];
  *(uint4*)(out + t * 32 + 16) = *(const uint4*)&ob[4];
}

// ------------------------------------------------------------------ convert
__global__ __launch_bounds__(256) void convert_kernel(
    const float* __restrict__ nd, const float* __restrict__ Wq,
    const float* __restrict__ Wk, const float* __restrict__ Wv,
    const float* __restrict__ Wo, u16* __restrict__ A16,
    u16* __restrict__ W16) {
  const int gi = blockIdx.x * 256 + threadIdx.x;
  const float* src;
  u16* dst;
  int off;
  if (gi < 524288) {
    src = nd; dst = A16; off = gi * 4;
  } else {
    const int w = (gi - 524288) >> 16;
    off = ((gi - 524288) & 65535) * 4;
    src = (w == 0) ? Wq : (w == 1) ? Wk : (w == 2) ? Wv : Wo;
    dst = W16 + (size_t)w * 262144;
  }
  const float4 v = *(const float4*)&src[off];
  ushort4 o;
  o.x = f2bf(v.x); o.y = f2bf(v.y); o.z = f2bf(v.z); o.w = f2bf(v.w);
  *(ushort4*)&dst[off] = o;
}

// ------------------------------------------------------------------- GEMM NT
template <int EPI>
__global__ __launch_bounds__(256) void gemm_nt(
    const u16* __restrict__ A16, const u16* __restrict__ W16,
    const float* __restrict__ bq, const float* __restrict__ bk,
    const float* __restrict__ bv, u16* __restrict__ Q16,
    u16* __restrict__ KF, u16* __restrict__ VF,
    const float* __restrict__ bo, float* __restrict__ OutF) {
  __shared__ u16 As[128 * 64];
  __shared__ u16 Ws[64 * 64];
  const int tid = threadIdx.x, lane = tid & 63, wid = tid >> 6;
  const int r0 = blockIdx.x * 128;
  int wsel, c0;
  const float* bias;
  float scale = 1.0f;
  if (EPI == 0) {
    wsel = blockIdx.y >> 3;
    c0 = (blockIdx.y & 7) * 64;
    bias = (wsel == 0) ? bq : (wsel == 1) ? bk : bv;
    if (wsel == 0) scale = 0.125f;  // hd^-0.5
  } else {
    wsel = 3;
    c0 = blockIdx.y * 64;
    bias = bo;
  }
  const u16* W = W16 + (size_t)wsel * (512 * 512);
  const int wm = (wid >> 1) * 64, wn = (wid & 1) * 32;

  f32x4 acc[4][2] = {};
  for (int k0 = 0; k0 < 512; k0 += 64) {
    __syncthreads();
#pragma unroll
    for (int p = 0; p < 4; ++p) {
      const int o = p * 4096 + tid * 16;
      const int row = o >> 7, kb = o & 127;
      gload_lds16((const char*)A16 + (size_t)(r0 + row) * 1024 + k0 * 2 +
                      (kb ^ ((row & 7) << 4)),
                  (char*)As + o);
    }
#pragma unroll
    for (int p = 0; p < 2; ++p) {
      const int o = p * 4096 + tid * 16;
      const int row = o >> 7, kb = o & 127;
      gload_lds16((const char*)W + (size_t)(c0 + row) * 1024 + k0 * 2 +
                      (kb ^ ((row & 7) << 4)),
                  (char*)Ws + o);
    }
    __syncthreads();
    bf16x8 af[4][2], bf[2][2];
#pragma unroll
    for (int mt = 0; mt < 4; ++mt)
#pragma unroll
      for (int ks = 0; ks < 2; ++ks) {
        const int row = wm + mt * 16 + (lane & 15);
        const int kb = ks * 64 + (lane >> 4) * 16;
        af[mt][ks] = *(const bf16x8*)((const char*)As + row * 128 +
                                      (kb ^ ((row & 7) << 4)));
      }
#pragma unroll
    for (int nt = 0; nt < 2; ++nt)
#pragma unroll
      for (int ks = 0; ks < 2; ++ks) {
        const int row = wn + nt * 16 + (lane & 15);
        const int kb = ks * 64 + (lane >> 4) * 16;
        bf[nt][ks] = *(const bf16x8*)((const char*)Ws + row * 128 +
                                      (kb ^ ((row & 7) << 4)));
      }
#pragma unroll
    for (int mt = 0; mt < 4; ++mt)
#pragma unroll
      for (int nt = 0; nt < 2; ++nt)
#pragma unroll
        for (int ks = 0; ks < 2; ++ks)
          acc[mt][nt] = __builtin_amdgcn_mfma_f32_16x16x32_bf16(
              af[mt][ks], bf[nt][ks], acc[mt][nt], 0, 0, 0);
  }
  float bvals[2];
#pragma unroll
  for (int nt = 0; nt < 2; ++nt)
    bvals[nt] = bias[c0 + wn + nt * 16 + (lane & 15)];
#pragma unroll
  for (int mt = 0; mt < 4; ++mt)
#pragma unroll
    for (int nt = 0; nt < 2; ++nt)
#pragma unroll
      for (int r = 0; r < 4; ++r) {
        const int row = r0 + wm + mt * 16 + (lane >> 4) * 4 + r;
        const int col = c0 + wn + nt * 16 + (lane & 15);
        const float v = (acc[mt][nt][r] + bvals[nt]) * scale;
        if (EPI == 0) {
          const int bb = row >> 10, n = row & 1023, hh = col >> 6,
                    dd = col & 63;
          if (wsel == 0) {
            Q16[((size_t)(bb * 8 + hh) * 1024 + n) * 64 + dd] = f2bf(v);
          } else if (wsel == 1) {
            // KF: A-frag for QK^T. lane&15=j-local, k=ks*32+g*8+e (d)
            const int jc = n >> 5, tt = (n >> 4) & 1, ln = n & 15;
            const int ks = dd >> 5, gg = (dd >> 3) & 3, e = dd & 7;
            KF[(((((size_t)(bb * 8 + hh) * 32 + jc) * 2 + tt) * 2 + ks) * 64 +
                gg * 16 + ln) * 8 + e] = f2bf(v);
          } else {
            // VF: B-frag for PV with sigma k-map:
            // j = jc*32 + (e<4 ? 4g+e : 16+4g+(e-4)), d = dt*16+ii
            const int jc = n >> 5, jl = n & 31;
            const int gg = (jl & 15) >> 2;
            const int e = (jl < 16) ? (jl & 3) : (4 + (jl & 3));
            const int dt = dd >> 4, ii = dd & 15;
            VF[((((size_t)(bb * 8 + hh) * 32 + jc) * 4 + dt) * 512) +
               (gg * 16 + ii) * 8 + e] = f2bf(v);
          }
        } else {
          OutF[(size_t)row * 512 + col] = v;
        }
      }
}

// --------------------------------------------------------- fused attention
// Block = (b, quarter of j, 16 q-rows) x 8 heads (8 waves, wave=head).
// Grid 1024 -> 4 blocks/CU (LDS 40KB, VGPR<=64 via launch_bounds(512,8)).
// Swapped QK^T; softmax = 7 fmax + 2 shfl; P in registers (PV A-frag);
// defer-max (THR=8) skips O-rescale when row max doesn't grow.
// Partials (unnorm O, m, l) to ws; combine_quarters merges.
__global__ __launch_bounds__(512, 8) void attn_fused4(
    const u16* __restrict__ Q16, const u16* __restrict__ KF,
    const u16* __restrict__ VF, const float* __restrict__ bias,
    const u8* __restrict__ mask8, const u8* __restrict__ mask_ws,
    const int* __restrict__ flag, float* __restrict__ Opart,
    float* __restrict__ Mm, float* __restrict__ Ll) {
  __shared__ __align__(16) char biasL[2][16384];
  __shared__ __align__(16) char maskL[2][4096];

  const int tid = threadIdx.x, lane = tid & 63, h = tid >> 6;
  const int bid = blockIdx.x;
  // slot = bid&7 = b*2 + (quarter&1): same-(b,quarter) blocks share an XCD
  const int s = bid & 7, gg_ = bid >> 3;
  const int b = s >> 1;
  const int quarter = ((gg_ & 1) << 1) | (s & 1);
  const int it = gg_ >> 1;
  const int i0 = it * 16;
  const u8* mk = (*flag != 0) ? mask8 : mask_ws;

  const int i = lane & 15, g = lane >> 4;  // i = this lane's softmax row
  const int g1 = g & 1, g2 = g >> 1;
  const int bh = b * 8 + h;

  // Q fragment (B-operand: lane&15 = i, k = ks*32+g*8+e)
  const u16* Qh = Q16 + (size_t)bh * 65536;
  bf16x8 qf[2];
#pragma unroll
  for (int ks = 0; ks < 2; ++ks)
    qf[ks] = *(const bf16x8*)&Qh[(size_t)(i0 + i) * 64 + ks * 32 + g * 8];

  float mo = -3e38f, lo = 0.f;
  f32x4 oacc[4] = {};

  // ---- staging source offsets (loop-invariant; +jc*256 per chunk)
  const size_t rowb = (size_t)(b * 1024 + i0) * 8192;  // bias f32 / mask u8
  int boff[8];
#pragma unroll
  for (int q = 0; q < 8; ++q) {
    const int w = q * 512 + tid;
    const int wi = w >> 8, oct = (w >> 6) & 3, slot = w & 63;
    const int se = slot ^ wi ^ ((oct & 1) << 4);
    boff[q] = wi * 8192 + oct * 64 + se;
  }
  int moff[2];
#pragma unroll
  for (int q = 0; q < 2; ++q) {
    const int bb2 = (q * 512 + tid) * 4;
    const int wi = bb2 >> 8, oct = (bb2 >> 6) & 3, sl = bb2 & 63;
    const int se = sl ^ ((wi << 2) & 0x3C);
    moff[q] = wi * 8192 + oct * 64 + se;
  }
  // ---- read-side constants
  const int Cb = (((g1 << 5) | h) ^ i ^ (g2 << 4)) << 2;  // bias byte slot*4
  const int baseb = i * 1024 + g2 * 256;
  const int Cm = ((g1 << 5) | h) ^ ((i << 2) & 0x3C);     // mask byte slot
  const int basem = i * 256 + g2 * 64;

  auto STAGE = [&](int buf, int jc) {
    const float* bsrc = bias + rowb + (size_t)jc * 256;
    const u8* msrc = mk + rowb + (size_t)jc * 256;
#pragma unroll
    for (int q = 0; q < 8; ++q)
      gload_lds4(bsrc + boff[q], biasL[buf] + (q * 512 + tid) * 4);
#pragma unroll
    for (int q = 0; q < 2; ++q)
      gload_lds4(msrc + moff[q], maskL[buf] + (q * 512 + tid) * 4);
  };

  const int jcBase = quarter * 8;
  STAGE(0, jcBase);

  for (int t = 0; t < 8; ++t) {
    asm volatile("s_waitcnt vmcnt(0)" ::: "memory");
    __builtin_amdgcn_s_barrier();
    const char* bb_ = biasL[t & 1];
    const char* mb_ = maskL[t & 1];
    const int jc = jcBase + t;
    const size_t kvb = (size_t)bh * 32 + jc;

    // K/V fragments (global, L2-hot; compiler auto-waits)
    bf16x8 kf[2][2];
#pragma unroll
    for (int t2 = 0; t2 < 2; ++t2)
#pragma unroll
      for (int ks = 0; ks < 2; ++ks)
        kf[t2][ks] =
            *(const bf16x8*)&KF[((kvb * 2 + t2) * 2 + ks) * 512 + lane * 8];
    bf16x8 vf[4];
#pragma unroll
    for (int dt = 0; dt < 4; ++dt)
      vf[dt] = *(const bf16x8*)&VF[(kvb * 4 + dt) * 512 + lane * 8];

    if (t < 7) STAGE((t + 1) & 1, jc + 1);

    // QK^T swapped: sa[t2][r] = S[j = 16*t2+4g+r][i]
    f32x4 sa[2] = {};
#pragma unroll
    for (int t2 = 0; t2 < 2; ++t2)
#pragma unroll
      for (int ks = 0; ks < 2; ++ks)
        sa[t2] = __builtin_amdgcn_mfma_f32_16x16x32_bf16(kf[t2][ks], qf[ks],
                                                         sa[t2], 0, 0, 0);

    // bias + mask
    float ss[2][4];
#pragma unroll
    for (int t2 = 0; t2 < 2; ++t2)
#pragma unroll
      for (int r = 0; r < 4; ++r) {
        const float bv =
            *(const float*)(bb_ + baseb + t2 * 512 + (Cb ^ (r << 5)));
        const u8 mv = *(const u8*)(mb_ + basem + t2 * 128 + (Cm ^ (r << 3)));
        ss[t2][r] = mv ? -1e30f : (sa[t2][r] + bv);
      }

    // softmax: in-thread over 8, shfl over lane bits 4-5; defer-max THR=8
    float cm = ss[0][0];
#pragma unroll
    for (int k = 1; k < 8; ++k) cm = fmaxf(cm, ss[k >> 2][k & 3]);
    cm = fmaxf(cm, __shfl_xor(cm, 16));
    cm = fmaxf(cm, __shfl_xor(cm, 32));
    if (!__all(cm <= mo + 8.f)) {
      const float mn = fmaxf(mo, cm);
      const float sc = __expf(mo - mn);
      mo = mn;
      lo *= sc;
      float scB[4];
#pragma unroll
      for (int r = 0; r < 4; ++r) scB[r] = __shfl(sc, g * 4 + r);
#pragma unroll
      for (int dt = 0; dt < 4; ++dt)
#pragma unroll
        for (int r = 0; r < 4; ++r) oacc[dt][r] *= scB[r];
    }
    float p[2][4], rs = 0.f;
#pragma unroll
    for (int k = 0; k < 8; ++k) {
      const float pv = __expf(ss[k >> 2][k & 3] - mo);
      p[k >> 2][k & 3] = pv;
      rs += pv;
    }
    rs += __shfl_xor(rs, 16);
    rs += __shfl_xor(rs, 32);
    lo += rs;

    // pack P as PV A-fragment (sigma: e<4 -> (t2=0,r=e); e>=4 -> (t2=1,r=e-4))
    union { u16 us[8]; bf16x8 v; } pk;
#pragma unroll
    for (int e = 0; e < 4; ++e) {
      pk.us[e] = f2bf(p[0][e]);
      pk.us[4 + e] = f2bf(p[1][e]);
    }
#pragma unroll
    for (int dt = 0; dt < 4; ++dt)
      oacc[dt] = __builtin_amdgcn_mfma_f32_16x16x32_bf16(pk.v, vf[dt],
                                                         oacc[dt], 0, 0, 0);
  }

  // ---- partials: unnormalized O + (m,l)
  float* Op = Opart + (size_t)quarter * 2097152 +
              ((size_t)(b * 1024 + i0)) * 512 + h * 64;
#pragma unroll
  for (int r = 0; r < 4; ++r)
#pragma unroll
    for (int dt = 0; dt < 4; ++dt)
      Op[(size_t)(g * 4 + r) * 512 + dt * 16 + i] = oacc[dt][r];
  if (lane < 16) {
    const size_t mi = ((size_t)(quarter * 4 + b) * 8 + h) * 1024 + i0 + lane;
    Mm[mi] = mo;
    Ll[mi] = lo;
  }
}

// ------------------------------------------------------------------ combine
__global__ __launch_bounds__(256) void combine_quarters(
    const float* __restrict__ Opart, const float* __restrict__ Mm,
    const float* __restrict__ Ll, u16* __restrict__ Ow) {
  const int t = blockIdx.x * 256 + threadIdx.x;  // 524288 threads, 4 cols
  const int col4 = t & 127, row = t >> 7;
  const int b = row >> 10, i = row & 1023, h = col4 >> 4;
  const size_t o0 = (size_t)row * 512 + col4 * 4;
  const size_t mi0 = ((size_t)b * 8 + h) * 1024 + i;
  float4 v[4];
  float m[4], l[4];
#pragma unroll
  for (int q = 0; q < 4; ++q) {
    v[q] = *(const float4*)&Opart[o0 + (size_t)q * 2097152];
    m[q] = Mm[mi0 + q * 32768];
    l[q] = Ll[mi0 + q * 32768];
  }
  const float M = fmaxf(fmaxf(m[0], m[1]), fmaxf(m[2], m[3]));
  float e[4], den = 0.f;
#pragma unroll
  for (int q = 0; q < 4; ++q) {
    e[q] = __expf(m[q] - M);
    den += l[q] * e[q];
  }
  const float inv = 1.0f / den;
  float4 acc = make_float4(0.f, 0.f, 0.f, 0.f);
#pragma unroll
  for (int q = 0; q < 4; ++q) {
    acc.x += v[q].x * e[q];
    acc.y += v[q].y * e[q];
    acc.z += v[q].z * e[q];
    acc.w += v[q].w * e[q];
  }
  ushort4 o;
  o.x = f2bf(acc.x * inv);
  o.y = f2bf(acc.y * inv);
  o.z = f2bf(acc.z * inv);
  o.w = f2bf(acc.w * inv);
  *(ushort4*)&Ow[o0] = o;
}

}  // namespace

extern "C" void kernel_launch(void* const* d_in, const int* in_sizes, int n_in,
                              void* d_out, int out_size, void* d_ws,
                              size_t ws_size, hipStream_t stream) {
  const float* ndata = (const float*)d_in[0];
  const float* bias = (const float*)d_in[1];
  const void* mask = d_in[2];
  const float* Wq = (const float*)d_in[3];
  const float* bq = (const float*)d_in[4];
  const float* Wk = (const float*)d_in[5];
  const float* bk = (const float*)d_in[6];
  const float* Wv = (const float*)d_in[7];
  const float* bvp = (const float*)d_in[8];
  const float* Wo = (const float*)d_in[9];
  const float* bo = (const float*)d_in[10];
  float* out = (float*)d_out;

  u16* A16 = (u16*)d_ws;
  u16* W16 = A16 + 2097152;
  u16* Q16 = W16 + 1048576;
  u16* KF = Q16 + 2097152;
  u16* VF = KF + 2097152;
  u16* Ow = VF + 2097152;
  float* Opart = (float*)(Ow + 2097152);  // 4 x 2097152 f32
  float* Mm = Opart + 8388608;            // 131072
  float* Ll = Mm + 131072;                // 131072
  u8* mask_ws = (u8*)(Ll + 131072);       // 33554432 B
  int* flag = (int*)(mask_ws + 33554432);

  detect_mask_kernel<<<1, 256, 0, stream>>>((const unsigned char*)mask, flag);
  canon_mask<<<4096, 256, 0, stream>>>((const int*)mask, flag, mask_ws);
  convert_kernel<<<3072, 256, 0, stream>>>(ndata, Wq, Wk, Wv, Wo, A16, W16);
  gemm_nt<0><<<dim3(32, 24), 256, 0, stream>>>(A16, W16, bq, bk, bvp, Q16, KF,
                                               VF, nullptr, nullptr);
  attn_fused4<<<1024, 512, 0, stream>>>(Q16, KF, VF, bias, (const u8*)mask,
                                        mask_ws, flag, Opart, Mm, Ll);
  combine_quarters<<<2048, 256, 0, stream>>>(Opart, Mm, Ll, Ow);
  gemm_nt<1><<<dim3(32, 8), 256, 0, stream>>>(Ow, W16, nullptr, nullptr,
                                              nullptr, nullptr, nullptr,
                                              nullptr, bo, out);
}

// Round 11
// 191.235 us; speedup vs baseline: 1.5028x; 1.5028x over previous
//
#include <hip/hip_runtime.h>
#include <hip/hip_bf16.h>
#include <cstdint>

// BiasedMHA bf16-MFMA pipeline: B=4, N=1024, FEAT=512, H=8, HD=64.
// detect mask -> canon (i32->u8, usually no-op) -> convert -> QKV GEMM
// (writes Q rows + fragment-major KF/VF with PV k-permutation baked) ->
// fused attention (swapped-QK^T in-register softmax, split-j x4, defer-max,
// launch_bounds(512,4): VGPR ~60 -> no spill, 4 blocks/CU) ->
// combine partials -> out-proj GEMM.

namespace {

typedef short bf16x8 __attribute__((ext_vector_type(8)));
typedef float f32x4 __attribute__((ext_vector_type(4)));
using u16 = unsigned short;
using u8 = unsigned char;

__device__ __forceinline__ u16 f2bf(float f) {
  union { float f; uint32_t i; } v;
  v.f = f;
  uint32_t r = v.i + 0x7fffu + ((v.i >> 16) & 1u);
  return (u16)(r >> 16);
}

__device__ __forceinline__ void gload_lds16(const void* g, void* l) {
  __builtin_amdgcn_global_load_lds(
      (__attribute__((address_space(1))) void*)g,
      (__attribute__((address_space(3))) void*)l, 16, 0, 0);
}
__device__ __forceinline__ void gload_lds4(const void* g, void* l) {
  __builtin_amdgcn_global_load_lds(
      (__attribute__((address_space(1))) void*)g,
      (__attribute__((address_space(3))) void*)l, 4, 0, 0);
}

// ---------------------------------------------------------------- mask dtype
__global__ void detect_mask_kernel(const unsigned char* __restrict__ m,
                                   int* __restrict__ flag) {
  __shared__ int red[256];
  int local = 0;
  for (int i = threadIdx.x; i < 65536; i += 256) local += (m[i] != 0) ? 1 : 0;
  red[threadIdx.x] = local;
  __syncthreads();
  for (int s = 128; s > 0; s >>= 1) {
    if ((int)threadIdx.x < s) red[threadIdx.x] += red[threadIdx.x + s];
    __syncthreads();
  }
  if (threadIdx.x == 0) *flag = (red[0] > 4915) ? 1 : 0;  // 7.5% threshold
}

__global__ __launch_bounds__(256) void canon_mask(const int* __restrict__ m32,
                                                  const int* __restrict__ flag,
                                                  u8* __restrict__ out) {
  if (*flag != 0) return;
  const size_t t = (size_t)blockIdx.x * 256 + threadIdx.x;
  const int4* src = (const int4*)m32 + t * 8;
  uchar4 ob[8];
#pragma unroll
  for (int q = 0; q < 8; ++q) {
    const int4 v = src[q];
    ob[q] = make_uchar4(v.x != 0, v.y != 0, v.z != 0, v.w != 0);
  }
  *(uint4*)(out + t * 32) = *(const uint4*)&ob[0];
  *(uint4*)(out + t * 32 + 16) = *(const uint4*)&ob[4];
}

// ------------------------------------------------------------------ convert
__global__ __launch_bounds__(256) void convert_kernel(
    const float* __restrict__ nd, const float* __restrict__ Wq,
    const float* __restrict__ Wk, const float* __restrict__ Wv,
    const float* __restrict__ Wo, u16* __restrict__ A16,
    u16* __restrict__ W16) {
  const int gi = blockIdx.x * 256 + threadIdx.x;
  const float* src;
  u16* dst;
  int off;
  if (gi < 524288) {
    src = nd; dst = A16; off = gi * 4;
  } else {
    const int w = (gi - 524288) >> 16;
    off = ((gi - 524288) & 65535) * 4;
    src = (w == 0) ? Wq : (w == 1) ? Wk : (w == 2) ? Wv : Wo;
    dst = W16 + (size_t)w * 262144;
  }
  const float4 v = *(const float4*)&src[off];
  ushort4 o;
  o.x = f2bf(v.x); o.y = f2bf(v.y); o.z = f2bf(v.z); o.w = f2bf(v.w);
  *(ushort4*)&dst[off] = o;
}

// ------------------------------------------------------------------- GEMM NT
template <int EPI>
__global__ __launch_bounds__(256) void gemm_nt(
    const u16* __restrict__ A16, const u16* __restrict__ W16,
    const float* __restrict__ bq, const float* __restrict__ bk,
    const float* __restrict__ bv, u16* __restrict__ Q16,
    u16* __restrict__ KF, u16* __restrict__ VF,
    const float* __restrict__ bo, float* __restrict__ OutF) {
  __shared__ u16 As[128 * 64];
  __shared__ u16 Ws[64 * 64];
  const int tid = threadIdx.x, lane = tid & 63, wid = tid >> 6;
  const int r0 = blockIdx.x * 128;
  int wsel, c0;
  const float* bias;
  float scale = 1.0f;
  if (EPI == 0) {
    wsel = blockIdx.y >> 3;
    c0 = (blockIdx.y & 7) * 64;
    bias = (wsel == 0) ? bq : (wsel == 1) ? bk : bv;
    if (wsel == 0) scale = 0.125f;  // hd^-0.5
  } else {
    wsel = 3;
    c0 = blockIdx.y * 64;
    bias = bo;
  }
  const u16* W = W16 + (size_t)wsel * (512 * 512);
  const int wm = (wid >> 1) * 64, wn = (wid & 1) * 32;

  f32x4 acc[4][2] = {};
  for (int k0 = 0; k0 < 512; k0 += 64) {
    __syncthreads();
#pragma unroll
    for (int p = 0; p < 4; ++p) {
      const int o = p * 4096 + tid * 16;
      const int row = o >> 7, kb = o & 127;
      gload_lds16((const char*)A16 + (size_t)(r0 + row) * 1024 + k0 * 2 +
                      (kb ^ ((row & 7) << 4)),
                  (char*)As + o);
    }
#pragma unroll
    for (int p = 0; p < 2; ++p) {
      const int o = p * 4096 + tid * 16;
      const int row = o >> 7, kb = o & 127;
      gload_lds16((const char*)W + (size_t)(c0 + row) * 1024 + k0 * 2 +
                      (kb ^ ((row & 7) << 4)),
                  (char*)Ws + o);
    }
    __syncthreads();
    bf16x8 af[4][2], bf[2][2];
#pragma unroll
    for (int mt = 0; mt < 4; ++mt)
#pragma unroll
      for (int ks = 0; ks < 2; ++ks) {
        const int row = wm + mt * 16 + (lane & 15);
        const int kb = ks * 64 + (lane >> 4) * 16;
        af[mt][ks] = *(const bf16x8*)((const char*)As + row * 128 +
                                      (kb ^ ((row & 7) << 4)));
      }
#pragma unroll
    for (int nt = 0; nt < 2; ++nt)
#pragma unroll
      for (int ks = 0; ks < 2; ++ks) {
        const int row = wn + nt * 16 + (lane & 15);
        const int kb = ks * 64 + (lane >> 4) * 16;
        bf[nt][ks] = *(const bf16x8*)((const char*)Ws + row * 128 +
                                      (kb ^ ((row & 7) << 4)));
      }
#pragma unroll
    for (int mt = 0; mt < 4; ++mt)
#pragma unroll
      for (int nt = 0; nt < 2; ++nt)
#pragma unroll
        for (int ks = 0; ks < 2; ++ks)
          acc[mt][nt] = __builtin_amdgcn_mfma_f32_16x16x32_bf16(
              af[mt][ks], bf[nt][ks], acc[mt][nt], 0, 0, 0);
  }
  float bvals[2];
#pragma unroll
  for (int nt = 0; nt < 2; ++nt)
    bvals[nt] = bias[c0 + wn + nt * 16 + (lane & 15)];
#pragma unroll
  for (int mt = 0; mt < 4; ++mt)
#pragma unroll
    for (int nt = 0; nt < 2; ++nt)
#pragma unroll
      for (int r = 0; r < 4; ++r) {
        const int row = r0 + wm + mt * 16 + (lane >> 4) * 4 + r;
        const int col = c0 + wn + nt * 16 + (lane & 15);
        const float v = (acc[mt][nt][r] + bvals[nt]) * scale;
        if (EPI == 0) {
          const int bb = row >> 10, n = row & 1023, hh = col >> 6,
                    dd = col & 63;
          if (wsel == 0) {
            Q16[((size_t)(bb * 8 + hh) * 1024 + n) * 64 + dd] = f2bf(v);
          } else if (wsel == 1) {
            // KF: A-frag for QK^T. lane&15=j-local, k=ks*32+g*8+e (d)
            const int jc = n >> 5, tt = (n >> 4) & 1, ln = n & 15;
            const int ks = dd >> 5, gg = (dd >> 3) & 3, e = dd & 7;
            KF[(((((size_t)(bb * 8 + hh) * 32 + jc) * 2 + tt) * 2 + ks) * 64 +
                gg * 16 + ln) * 8 + e] = f2bf(v);
          } else {
            // VF: B-frag for PV with sigma k-map:
            // j = jc*32 + (e<4 ? 4g+e : 16+4g+(e-4)), d = dt*16+ii
            const int jc = n >> 5, jl = n & 31;
            const int gg = (jl & 15) >> 2;
            const int e = (jl < 16) ? (jl & 3) : (4 + (jl & 3));
            const int dt = dd >> 4, ii = dd & 15;
            VF[((((size_t)(bb * 8 + hh) * 32 + jc) * 4 + dt) * 512) +
               (gg * 16 + ii) * 8 + e] = f2bf(v);
          }
        } else {
          OutF[(size_t)row * 512 + col] = v;
        }
      }
}

// --------------------------------------------------------- fused attention
// Block = (b, quarter of j, 16 q-rows) x 8 heads (8 waves, wave=head).
// Grid 1024; launch_bounds(512,4) -> VGPR ~60 (<=64) -> 8 waves/SIMD ->
// 4 blocks/CU co-resident (LDS 40KB x 4 = 160KB exactly).
// Swapped QK^T; softmax = 7 fmax + 2 shfl; P in registers (PV A-frag);
// defer-max (THR=8) skips O-rescale when row max doesn't grow.
__global__ __launch_bounds__(512, 4) void attn_fused4(
    const u16* __restrict__ Q16, const u16* __restrict__ KF,
    const u16* __restrict__ VF, const float* __restrict__ bias,
    const u8* __restrict__ mask8, const u8* __restrict__ mask_ws,
    const int* __restrict__ flag, float* __restrict__ Opart,
    float* __restrict__ Mm, float* __restrict__ Ll) {
  __shared__ __align__(16) char biasL[2][16384];
  __shared__ __align__(16) char maskL[2][4096];

  const int tid = threadIdx.x, lane = tid & 63, h = tid >> 6;
  const int bid = blockIdx.x;
  // slot = bid&7 = b*2 + (quarter&1): same-(b,quarter) blocks share an XCD
  const int s = bid & 7, gg_ = bid >> 3;
  const int b = s >> 1;
  const int quarter = ((gg_ & 1) << 1) | (s & 1);
  const int it = gg_ >> 1;
  const int i0 = it * 16;
  const u8* mk = (*flag != 0) ? mask8 : mask_ws;

  const int i = lane & 15, g = lane >> 4;  // i = this lane's softmax row
  const int g1 = g & 1, g2 = g >> 1;
  const int bh = b * 8 + h;

  // Q fragment (B-operand: lane&15 = i, k = ks*32+g*8+e)
  const u16* Qh = Q16 + (size_t)bh * 65536;
  bf16x8 qf[2];
#pragma unroll
  for (int ks = 0; ks < 2; ++ks)
    qf[ks] = *(const bf16x8*)&Qh[(size_t)(i0 + i) * 64 + ks * 32 + g * 8];

  float mo = -3e38f, lo = 0.f;
  f32x4 oacc[4] = {};

  // ---- staging source offsets (loop-invariant; +jc*256 per chunk)
  const size_t rowb = (size_t)(b * 1024 + i0) * 8192;  // bias f32 / mask u8
  int boff[8];
#pragma unroll
  for (int q = 0; q < 8; ++q) {
    const int w = q * 512 + tid;
    const int wi = w >> 8, oct = (w >> 6) & 3, slot = w & 63;
    const int se = slot ^ wi ^ ((oct & 1) << 4);
    boff[q] = wi * 8192 + oct * 64 + se;
  }
  int moff[2];
#pragma unroll
  for (int q = 0; q < 2; ++q) {
    const int bb2 = (q * 512 + tid) * 4;
    const int wi = bb2 >> 8, oct = (bb2 >> 6) & 3, sl = bb2 & 63;
    const int se = sl ^ ((wi << 2) & 0x3C);
    moff[q] = wi * 8192 + oct * 64 + se;
  }
  // ---- read-side constants
  const int Cb = (((g1 << 5) | h) ^ i ^ (g2 << 4)) << 2;  // bias byte slot*4
  const int baseb = i * 1024 + g2 * 256;
  const int Cm = ((g1 << 5) | h) ^ ((i << 2) & 0x3C);     // mask byte slot
  const int basem = i * 256 + g2 * 64;

  auto STAGE = [&](int buf, int jc) {
    const float* bsrc = bias + rowb + (size_t)jc * 256;
    const u8* msrc = mk + rowb + (size_t)jc * 256;
#pragma unroll
    for (int q = 0; q < 8; ++q)
      gload_lds4(bsrc + boff[q], biasL[buf] + (q * 512 + tid) * 4);
#pragma unroll
    for (int q = 0; q < 2; ++q)
      gload_lds4(msrc + moff[q], maskL[buf] + (q * 512 + tid) * 4);
  };

  const int jcBase = quarter * 8;
  STAGE(0, jcBase);

  for (int t = 0; t < 8; ++t) {
    asm volatile("s_waitcnt vmcnt(0)" ::: "memory");
    __builtin_amdgcn_s_barrier();
    const char* bb_ = biasL[t & 1];
    const char* mb_ = maskL[t & 1];
    const int jc = jcBase + t;
    const size_t kvb = (size_t)bh * 32 + jc;

    // K/V fragments (global, L2-hot; compiler auto-waits)
    bf16x8 kf[2][2];
#pragma unroll
    for (int t2 = 0; t2 < 2; ++t2)
#pragma unroll
      for (int ks = 0; ks < 2; ++ks)
        kf[t2][ks] =
            *(const bf16x8*)&KF[((kvb * 2 + t2) * 2 + ks) * 512 + lane * 8];
    bf16x8 vf[4];
#pragma unroll
    for (int dt = 0; dt < 4; ++dt)
      vf[dt] = *(const bf16x8*)&VF[(kvb * 4 + dt) * 512 + lane * 8];

    if (t < 7) STAGE((t + 1) & 1, jc + 1);

    // QK^T swapped: sa[t2][r] = S[j = 16*t2+4g+r][i]
    f32x4 sa[2] = {};
#pragma unroll
    for (int t2 = 0; t2 < 2; ++t2)
#pragma unroll
      for (int ks = 0; ks < 2; ++ks)
        sa[t2] = __builtin_amdgcn_mfma_f32_16x16x32_bf16(kf[t2][ks], qf[ks],
                                                         sa[t2], 0, 0, 0);

    // bias + mask
    float ss[2][4];
#pragma unroll
    for (int t2 = 0; t2 < 2; ++t2)
#pragma unroll
      for (int r = 0; r < 4; ++r) {
        const float bv =
            *(const float*)(bb_ + baseb + t2 * 512 + (Cb ^ (r << 5)));
        const u8 mv = *(const u8*)(mb_ + basem + t2 * 128 + (Cm ^ (r << 3)));
        ss[t2][r] = mv ? -1e30f : (sa[t2][r] + bv);
      }

    // softmax: in-thread over 8, shfl over lane bits 4-5; defer-max THR=8
    float cm = ss[0][0];
#pragma unroll
    for (int k = 1; k < 8; ++k) cm = fmaxf(cm, ss[k >> 2][k & 3]);
    cm = fmaxf(cm, __shfl_xor(cm, 16));
    cm = fmaxf(cm, __shfl_xor(cm, 32));
    if (!__all(cm <= mo + 8.f)) {
      const float mn = fmaxf(mo, cm);
      const float sc = __expf(mo - mn);
      mo = mn;
      lo *= sc;
      float scB[4];
#pragma unroll
      for (int r = 0; r < 4; ++r) scB[r] = __shfl(sc, g * 4 + r);
#pragma unroll
      for (int dt = 0; dt < 4; ++dt)
#pragma unroll
        for (int r = 0; r < 4; ++r) oacc[dt][r] *= scB[r];
    }
    float p[2][4], rs = 0.f;
#pragma unroll
    for (int k = 0; k < 8; ++k) {
      const float pv = __expf(ss[k >> 2][k & 3] - mo);
      p[k >> 2][k & 3] = pv;
      rs += pv;
    }
    rs += __shfl_xor(rs, 16);
    rs += __shfl_xor(rs, 32);
    lo += rs;

    // pack P as PV A-fragment (sigma: e<4 -> (t2=0,r=e); e>=4 -> (t2=1,r=e-4))
    union { u16 us[8]; bf16x8 v; } pk;
#pragma unroll
    for (int e = 0; e < 4; ++e) {
      pk.us[e] = f2bf(p[0][e]);
      pk.us[4 + e] = f2bf(p[1][e]);
    }
#pragma unroll
    for (int dt = 0; dt < 4; ++dt)
      oacc[dt] = __builtin_amdgcn_mfma_f32_16x16x32_bf16(pk.v, vf[dt],
                                                         oacc[dt], 0, 0, 0);
  }

  // ---- partials: unnormalized O + (m,l)
  float* Op = Opart + (size_t)quarter * 2097152 +
              ((size_t)(b * 1024 + i0)) * 512 + h * 64;
#pragma unroll
  for (int r = 0; r < 4; ++r)
#pragma unroll
    for (int dt = 0; dt < 4; ++dt)
      Op[(size_t)(g * 4 + r) * 512 + dt * 16 + i] = oacc[dt][r];
  if (lane < 16) {
    const size_t mi = ((size_t)(quarter * 4 + b) * 8 + h) * 1024 + i0 + lane;
    Mm[mi] = mo;
    Ll[mi] = lo;
  }
}

// ------------------------------------------------------------------ combine
__global__ __launch_bounds__(256) void combine_quarters(
    const float* __restrict__ Opart, const float* __restrict__ Mm,
    const float* __restrict__ Ll, u16* __restrict__ Ow) {
  const int t = blockIdx.x * 256 + threadIdx.x;  // 524288 threads, 4 cols
  const int col4 = t & 127, row = t >> 7;
  const int b = row >> 10, i = row & 1023, h = col4 >> 4;
  const size_t o0 = (size_t)row * 512 + col4 * 4;
  const size_t mi0 = ((size_t)b * 8 + h) * 1024 + i;
  float4 v[4];
  float m[4], l[4];
#pragma unroll
  for (int q = 0; q < 4; ++q) {
    v[q] = *(const float4*)&Opart[o0 + (size_t)q * 2097152];
    m[q] = Mm[mi0 + q * 32768];
    l[q] = Ll[mi0 + q * 32768];
  }
  const float M = fmaxf(fmaxf(m[0], m[1]), fmaxf(m[2], m[3]));
  float e[4], den = 0.f;
#pragma unroll
  for (int q = 0; q < 4; ++q) {
    e[q] = __expf(m[q] - M);
    den += l[q] * e[q];
  }
  const float inv = 1.0f / den;
  float4 acc = make_float4(0.f, 0.f, 0.f, 0.f);
#pragma unroll
  for (int q = 0; q < 4; ++q) {
    acc.x += v[q].x * e[q];
    acc.y += v[q].y * e[q];
    acc.z += v[q].z * e[q];
    acc.w += v[q].w * e[q];
  }
  ushort4 o;
  o.x = f2bf(acc.x * inv);
  o.y = f2bf(acc.y * inv);
  o.z = f2bf(acc.z * inv);
  o.w = f2bf(acc.w * inv);
  *(ushort4*)&Ow[o0] = o;
}

}  // namespace

extern "C" void kernel_launch(void* const* d_in, const int* in_sizes, int n_in,
                              void* d_out, int out_size, void* d_ws,
                              size_t ws_size, hipStream_t stream) {
  const float* ndata = (const float*)d_in[0];
  const float* bias = (const float*)d_in[1];
  const void* mask = d_in[2];
  const float* Wq = (const float*)d_in[3];
  const float* bq = (const float*)d_in[4];
  const float* Wk = (const float*)d_in[5];
  const float* bk = (const float*)d_in[6];
  const float* Wv = (const float*)d_in[7];
  const float* bvp = (const float*)d_in[8];
  const float* Wo = (const float*)d_in[9];
  const float* bo = (const float*)d_in[10];
  float* out = (float*)d_out;

  u16* A16 = (u16*)d_ws;
  u16* W16 = A16 + 2097152;
  u16* Q16 = W16 + 1048576;
  u16* KF = Q16 + 2097152;
  u16* VF = KF + 2097152;
  u16* Ow = VF + 2097152;
  float* Opart = (float*)(Ow + 2097152);  // 4 x 2097152 f32
  float* Mm = Opart + 8388608;            // 131072
  float* Ll = Mm + 131072;                // 131072
  u8* mask_ws = (u8*)(Ll + 131072);       // 33554432 B
  int* flag = (int*)(mask_ws + 33554432);

  detect_mask_kernel<<<1, 256, 0, stream>>>((const unsigned char*)mask, flag);
  canon_mask<<<4096, 256, 0, stream>>>((const int*)mask, flag, mask_ws);
  convert_kernel<<<3072, 256, 0, stream>>>(ndata, Wq, Wk, Wv, Wo, A16, W16);
  gemm_nt<0><<<dim3(32, 24), 256, 0, stream>>>(A16, W16, bq, bk, bvp, Q16, KF,
                                               VF, nullptr, nullptr);
  attn_fused4<<<1024, 512, 0, stream>>>(Q16, KF, VF, bias, (const u8*)mask,
                                        mask_ws, flag, Opart, Mm, Ll);
  combine_quarters<<<2048, 256, 0, stream>>>(Opart, Mm, Ll, Ow);
  gemm_nt<1><<<dim3(32, 8), 256, 0, stream>>>(Ow, W16, nullptr, nullptr,
                                              nullptr, nullptr, nullptr,
                                              nullptr, bo, out);
}

// Round 12
// 170.043 us; speedup vs baseline: 1.6901x; 1.1246x over previous
//
#include <hip/hip_runtime.h>
#include <hip/hip_bf16.h>
#include <cstdint>

// BiasedMHA bf16-MFMA pipeline: B=4, N=1024, FEAT=512, H=8, HD=64.
// detect mask -> canon (i32->u8, usually no-op) -> convert -> QKV GEMM
// (writes Q rows + fragment-major KF/VF with PV k-permutation baked) ->
// fused attention (swapped-QK^T in-register softmax, split-j x2, defer-max,
// TRIPLE-buffered bias/mask staging with counted vmcnt(10) -- never drain
// to 0 in the main loop) -> combine partials -> out-proj GEMM.

namespace {

typedef short bf16x8 __attribute__((ext_vector_type(8)));
typedef float f32x4 __attribute__((ext_vector_type(4)));
using u16 = unsigned short;
using u8 = unsigned char;

__device__ __forceinline__ u16 f2bf(float f) {
  union { float f; uint32_t i; } v;
  v.f = f;
  uint32_t r = v.i + 0x7fffu + ((v.i >> 16) & 1u);
  return (u16)(r >> 16);
}

__device__ __forceinline__ void gload_lds16(const void* g, void* l) {
  __builtin_amdgcn_global_load_lds(
      (__attribute__((address_space(1))) void*)g,
      (__attribute__((address_space(3))) void*)l, 16, 0, 0);
}
__device__ __forceinline__ void gload_lds4(const void* g, void* l) {
  __builtin_amdgcn_global_load_lds(
      (__attribute__((address_space(1))) void*)g,
      (__attribute__((address_space(3))) void*)l, 4, 0, 0);
}

// ---------------------------------------------------------------- mask dtype
__global__ void detect_mask_kernel(const unsigned char* __restrict__ m,
                                   int* __restrict__ flag) {
  __shared__ int red[256];
  int local = 0;
  for (int i = threadIdx.x; i < 65536; i += 256) local += (m[i] != 0) ? 1 : 0;
  red[threadIdx.x] = local;
  __syncthreads();
  for (int s = 128; s > 0; s >>= 1) {
    if ((int)threadIdx.x < s) red[threadIdx.x] += red[threadIdx.x + s];
    __syncthreads();
  }
  if (threadIdx.x == 0) *flag = (red[0] > 4915) ? 1 : 0;  // 7.5% threshold
}

__global__ __launch_bounds__(256) void canon_mask(const int* __restrict__ m32,
                                                  const int* __restrict__ flag,
                                                  u8* __restrict__ out) {
  if (*flag != 0) return;
  const size_t t = (size_t)blockIdx.x * 256 + threadIdx.x;
  const int4* src = (const int4*)m32 + t * 8;
  uchar4 ob[8];
#pragma unroll
  for (int q = 0; q < 8; ++q) {
    const int4 v = src[q];
    ob[q] = make_uchar4(v.x != 0, v.y != 0, v.z != 0, v.w != 0);
  }
  *(uint4*)(out + t * 32) = *(const uint4*)&ob[0];
  *(uint4*)(out + t * 32 + 16) = *(const uint4*)&ob[4];
}

// ------------------------------------------------------------------ convert
__global__ __launch_bounds__(256) void convert_kernel(
    const float* __restrict__ nd, const float* __restrict__ Wq,
    const float* __restrict__ Wk, const float* __restrict__ Wv,
    const float* __restrict__ Wo, u16* __restrict__ A16,
    u16* __restrict__ W16) {
  const int gi = blockIdx.x * 256 + threadIdx.x;
  const float* src;
  u16* dst;
  int off;
  if (gi < 524288) {
    src = nd; dst = A16; off = gi * 4;
  } else {
    const int w = (gi - 524288) >> 16;
    off = ((gi - 524288) & 65535) * 4;
    src = (w == 0) ? Wq : (w == 1) ? Wk : (w == 2) ? Wv : Wo;
    dst = W16 + (size_t)w * 262144;
  }
  const float4 v = *(const float4*)&src[off];
  ushort4 o;
  o.x = f2bf(v.x); o.y = f2bf(v.y); o.z = f2bf(v.z); o.w = f2bf(v.w);
  *(ushort4*)&dst[off] = o;
}

// ------------------------------------------------------------------- GEMM NT
template <int EPI>
__global__ __launch_bounds__(256) void gemm_nt(
    const u16* __restrict__ A16, const u16* __restrict__ W16,
    const float* __restrict__ bq, const float* __restrict__ bk,
    const float* __restrict__ bv, u16* __restrict__ Q16,
    u16* __restrict__ KF, u16* __restrict__ VF,
    const float* __restrict__ bo, float* __restrict__ OutF) {
  __shared__ u16 As[128 * 64];
  __shared__ u16 Ws[64 * 64];
  const int tid = threadIdx.x, lane = tid & 63, wid = tid >> 6;
  const int r0 = blockIdx.x * 128;
  int wsel, c0;
  const float* bias;
  float scale = 1.0f;
  if (EPI == 0) {
    wsel = blockIdx.y >> 3;
    c0 = (blockIdx.y & 7) * 64;
    bias = (wsel == 0) ? bq : (wsel == 1) ? bk : bv;
    if (wsel == 0) scale = 0.125f;  // hd^-0.5
  } else {
    wsel = 3;
    c0 = blockIdx.y * 64;
    bias = bo;
  }
  const u16* W = W16 + (size_t)wsel * (512 * 512);
  const int wm = (wid >> 1) * 64, wn = (wid & 1) * 32;

  f32x4 acc[4][2] = {};
  for (int k0 = 0; k0 < 512; k0 += 64) {
    __syncthreads();
#pragma unroll
    for (int p = 0; p < 4; ++p) {
      const int o = p * 4096 + tid * 16;
      const int row = o >> 7, kb = o & 127;
      gload_lds16((const char*)A16 + (size_t)(r0 + row) * 1024 + k0 * 2 +
                      (kb ^ ((row & 7) << 4)),
                  (char*)As + o);
    }
#pragma unroll
    for (int p = 0; p < 2; ++p) {
      const int o = p * 4096 + tid * 16;
      const int row = o >> 7, kb = o & 127;
      gload_lds16((const char*)W + (size_t)(c0 + row) * 1024 + k0 * 2 +
                      (kb ^ ((row & 7) << 4)),
                  (char*)Ws + o);
    }
    __syncthreads();
    bf16x8 af[4][2], bf[2][2];
#pragma unroll
    for (int mt = 0; mt < 4; ++mt)
#pragma unroll
      for (int ks = 0; ks < 2; ++ks) {
        const int row = wm + mt * 16 + (lane & 15);
        const int kb = ks * 64 + (lane >> 4) * 16;
        af[mt][ks] = *(const bf16x8*)((const char*)As + row * 128 +
                                      (kb ^ ((row & 7) << 4)));
      }
#pragma unroll
    for (int nt = 0; nt < 2; ++nt)
#pragma unroll
      for (int ks = 0; ks < 2; ++ks) {
        const int row = wn + nt * 16 + (lane & 15);
        const int kb = ks * 64 + (lane >> 4) * 16;
        bf[nt][ks] = *(const bf16x8*)((const char*)Ws + row * 128 +
                                      (kb ^ ((row & 7) << 4)));
      }
#pragma unroll
    for (int mt = 0; mt < 4; ++mt)
#pragma unroll
      for (int nt = 0; nt < 2; ++nt)
#pragma unroll
        for (int ks = 0; ks < 2; ++ks)
          acc[mt][nt] = __builtin_amdgcn_mfma_f32_16x16x32_bf16(
              af[mt][ks], bf[nt][ks], acc[mt][nt], 0, 0, 0);
  }
  float bvals[2];
#pragma unroll
  for (int nt = 0; nt < 2; ++nt)
    bvals[nt] = bias[c0 + wn + nt * 16 + (lane & 15)];
#pragma unroll
  for (int mt = 0; mt < 4; ++mt)
#pragma unroll
    for (int nt = 0; nt < 2; ++nt)
#pragma unroll
      for (int r = 0; r < 4; ++r) {
        const int row = r0 + wm + mt * 16 + (lane >> 4) * 4 + r;
        const int col = c0 + wn + nt * 16 + (lane & 15);
        const float v = (acc[mt][nt][r] + bvals[nt]) * scale;
        if (EPI == 0) {
          const int bb = row >> 10, n = row & 1023, hh = col >> 6,
                    dd = col & 63;
          if (wsel == 0) {
            Q16[((size_t)(bb * 8 + hh) * 1024 + n) * 64 + dd] = f2bf(v);
          } else if (wsel == 1) {
            // KF: A-frag for QK^T. lane&15=j-local, k=ks*32+g*8+e (d)
            const int jc = n >> 5, tt = (n >> 4) & 1, ln = n & 15;
            const int ks = dd >> 5, gg = (dd >> 3) & 3, e = dd & 7;
            KF[(((((size_t)(bb * 8 + hh) * 32 + jc) * 2 + tt) * 2 + ks) * 64 +
                gg * 16 + ln) * 8 + e] = f2bf(v);
          } else {
            // VF: B-frag for PV with sigma k-map:
            // j = jc*32 + (e<4 ? 4g+e : 16+4g+(e-4)), d = dt*16+ii
            const int jc = n >> 5, jl = n & 31;
            const int gg = (jl & 15) >> 2;
            const int e = (jl < 16) ? (jl & 3) : (4 + (jl & 3));
            const int dt = dd >> 4, ii = dd & 15;
            VF[((((size_t)(bb * 8 + hh) * 32 + jc) * 4 + dt) * 512) +
               (gg * 16 + ii) * 8 + e] = f2bf(v);
          }
        } else {
          OutF[(size_t)row * 512 + col] = v;
        }
      }
}

// --------------------------------------------------------- fused attention
// Block = (b, half of j, 16 q-rows) x 8 heads (8 waves, wave=head).
// Grid 512; LDS 60KB -> 2 blocks/CU. Triple-buffered bias/mask staging with
// counted vmcnt(10): staging for chunk t+1 issues during chunk t-1, giving a
// 2-chunk latency window; loads are never drained to 0 in the loop (T3/T4).
// Swapped QK^T; softmax = 7 fmax + 2 shfl; P in registers (PV A-frag);
// defer-max (THR=8). Partials (unnorm O, m, l) to ws.
__global__ __launch_bounds__(512, 4) void attn_fused5(
    const u16* __restrict__ Q16, const u16* __restrict__ KF,
    const u16* __restrict__ VF, const float* __restrict__ bias,
    const u8* __restrict__ mask8, const u8* __restrict__ mask_ws,
    const int* __restrict__ flag, float* __restrict__ Opart,
    float* __restrict__ Mm, float* __restrict__ Ll) {
  __shared__ __align__(16) char biasL[3][16384];
  __shared__ __align__(16) char maskL[3][4096];

  const int tid = threadIdx.x, lane = tid & 63, h = tid >> 6;
  const int bid = blockIdx.x;
  // slot = bid&7: blocks of batch b land on XCD slots {b, b+4} -> K/V L2-hot
  const int b = bid & 3, half = (bid >> 2) & 1, it = bid >> 3;
  const int i0 = it * 16;
  const u8* mk = (*flag != 0) ? mask8 : mask_ws;

  const int i = lane & 15, g = lane >> 4;  // i = this lane's softmax row
  const int g1 = g & 1, g2 = g >> 1;
  const int bh = b * 8 + h;

  // Q fragment (B-operand: lane&15 = i, k = ks*32+g*8+e)
  const u16* Qh = Q16 + (size_t)bh * 65536;
  bf16x8 qf[2];
#pragma unroll
  for (int ks = 0; ks < 2; ++ks)
    qf[ks] = *(const bf16x8*)&Qh[(size_t)(i0 + i) * 64 + ks * 32 + g * 8];

  float mo = -3e38f, lo = 0.f;
  f32x4 oacc[4] = {};

  // ---- staging source offsets (loop-invariant; +jc*256 per chunk)
  const size_t rowb = (size_t)(b * 1024 + i0) * 8192;  // bias f32 / mask u8
  int boff[8];
#pragma unroll
  for (int q = 0; q < 8; ++q) {
    const int w = q * 512 + tid;
    const int wi = w >> 8, oct = (w >> 6) & 3, slot = w & 63;
    const int se = slot ^ wi ^ ((oct & 1) << 4);
    boff[q] = wi * 8192 + oct * 64 + se;
  }
  int moff[2];
#pragma unroll
  for (int q = 0; q < 2; ++q) {
    const int bb2 = (q * 512 + tid) * 4;
    const int wi = bb2 >> 8, oct = (bb2 >> 6) & 3, sl = bb2 & 63;
    const int se = sl ^ ((wi << 2) & 0x3C);
    moff[q] = wi * 8192 + oct * 64 + se;
  }
  // ---- read-side constants
  const int Cb = (((g1 << 5) | h) ^ i ^ (g2 << 4)) << 2;  // bias byte slot*4
  const int baseb = i * 1024 + g2 * 256;
  const int Cm = ((g1 << 5) | h) ^ ((i << 2) & 0x3C);     // mask byte slot
  const int basem = i * 256 + g2 * 64;

  auto STAGE = [&](int buf, int jc) {
    const float* bsrc = bias + rowb + (size_t)jc * 256;
    const u8* msrc = mk + rowb + (size_t)jc * 256;
#pragma unroll
    for (int q = 0; q < 8; ++q)
      gload_lds4(bsrc + boff[q], biasL[buf] + (q * 512 + tid) * 4);
#pragma unroll
    for (int q = 0; q < 2; ++q)
      gload_lds4(msrc + moff[q], maskL[buf] + (q * 512 + tid) * 4);
  };

  const int jcBase = half * 16;
  STAGE(0, jcBase);
  STAGE(1, jcBase + 1);
  // staging(0) complete when <=10 outstanding (staging(1) still in flight)
  asm volatile("s_waitcnt vmcnt(10)" ::: "memory");
  __builtin_amdgcn_s_barrier();

  for (int t = 0; t < 16; ++t) {
    const int buf = t % 3;
    const char* bb_ = biasL[buf];
    const char* mb_ = maskL[buf];
    const int jc = jcBase + t;
    const size_t kvb = (size_t)bh * 32 + jc;

    // K/V fragments (global, L2-hot; compiler inserts precise counted waits)
    bf16x8 kf[2][2];
#pragma unroll
    for (int t2 = 0; t2 < 2; ++t2)
#pragma unroll
      for (int ks = 0; ks < 2; ++ks)
        kf[t2][ks] =
            *(const bf16x8*)&KF[((kvb * 2 + t2) * 2 + ks) * 512 + lane * 8];
    bf16x8 vf[4];
#pragma unroll
    for (int dt = 0; dt < 4; ++dt)
      vf[dt] = *(const bf16x8*)&VF[(kvb * 4 + dt) * 512 + lane * 8];

    if (t < 14) STAGE((t + 2) % 3, jc + 2);  // writes buf read in chunk t-1

    // QK^T swapped: sa[t2][r] = S[j = 16*t2+4g+r][i]
    f32x4 sa[2] = {};
#pragma unroll
    for (int t2 = 0; t2 < 2; ++t2)
#pragma unroll
      for (int ks = 0; ks < 2; ++ks)
        sa[t2] = __builtin_amdgcn_mfma_f32_16x16x32_bf16(kf[t2][ks], qf[ks],
                                                         sa[t2], 0, 0, 0);

    // bias + mask
    float ss[2][4];
#pragma unroll
    for (int t2 = 0; t2 < 2; ++t2)
#pragma unroll
      for (int r = 0; r < 4; ++r) {
        const float bv =
            *(const float*)(bb_ + baseb + t2 * 512 + (Cb ^ (r << 5)));
        const u8 mv = *(const u8*)(mb_ + basem + t2 * 128 + (Cm ^ (r << 3)));
        ss[t2][r] = mv ? -1e30f : (sa[t2][r] + bv);
      }

    // softmax: in-thread over 8, shfl over lane bits 4-5; defer-max THR=8
    float cm = ss[0][0];
#pragma unroll
    for (int k = 1; k < 8; ++k) cm = fmaxf(cm, ss[k >> 2][k & 3]);
    cm = fmaxf(cm, __shfl_xor(cm, 16));
    cm = fmaxf(cm, __shfl_xor(cm, 32));
    if (!__all(cm <= mo + 8.f)) {
      const float mn = fmaxf(mo, cm);
      const float sc = __expf(mo - mn);
      mo = mn;
      lo *= sc;
      float scB[4];
#pragma unroll
      for (int r = 0; r < 4; ++r) scB[r] = __shfl(sc, g * 4 + r);
#pragma unroll
      for (int dt = 0; dt < 4; ++dt)
#pragma unroll
        for (int r = 0; r < 4; ++r) oacc[dt][r] *= scB[r];
    }
    float p[2][4], rs = 0.f;
#pragma unroll
    for (int k = 0; k < 8; ++k) {
      const float pv = __expf(ss[k >> 2][k & 3] - mo);
      p[k >> 2][k & 3] = pv;
      rs += pv;
    }
    rs += __shfl_xor(rs, 16);
    rs += __shfl_xor(rs, 32);
    lo += rs;

    // pack P as PV A-fragment (sigma: e<4 -> (t2=0,r=e); e>=4 -> (t2=1,r=e-4))
    union { u16 us[8]; bf16x8 v; } pk;
#pragma unroll
    for (int e = 0; e < 4; ++e) {
      pk.us[e] = f2bf(p[0][e]);
      pk.us[4 + e] = f2bf(p[1][e]);
    }
#pragma unroll
    for (int dt = 0; dt < 4; ++dt)
      oacc[dt] = __builtin_amdgcn_mfma_f32_16x16x32_bf16(pk.v, vf[dt],
                                                         oacc[dt], 0, 0, 0);

    // counted wait: staging(t+1) proven complete while staging(t+2) flies
    if (t < 14) {
      asm volatile("s_waitcnt vmcnt(10)" ::: "memory");
      __builtin_amdgcn_s_barrier();
    } else if (t == 14) {
      asm volatile("s_waitcnt vmcnt(0)" ::: "memory");
      __builtin_amdgcn_s_barrier();
    }
  }

  // ---- partials: unnormalized O + (m,l)
  float* Op = Opart + (size_t)half * 2097152 +
              ((size_t)(b * 1024 + i0)) * 512 + h * 64;
#pragma unroll
  for (int r = 0; r < 4; ++r)
#pragma unroll
    for (int dt = 0; dt < 4; ++dt)
      Op[(size_t)(g * 4 + r) * 512 + dt * 16 + i] = oacc[dt][r];
  if (lane < 16) {
    const size_t mi = ((size_t)(half * 4 + b) * 8 + h) * 1024 + i0 + lane;
    Mm[mi] = mo;
    Ll[mi] = lo;
  }
}

// ------------------------------------------------------------------ combine
__global__ __launch_bounds__(256) void combine_halves(
    const float* __restrict__ Opart, const float* __restrict__ Mm,
    const float* __restrict__ Ll, u16* __restrict__ Ow) {
  const int t = blockIdx.x * 256 + threadIdx.x;  // 524288 threads, 4 cols
  const int col4 = t & 127, row = t >> 7;
  const int b = row >> 10, i = row & 1023, h = col4 >> 4;
  const size_t o0 = (size_t)row * 512 + col4 * 4;
  const float4 v0 = *(const float4*)&Opart[o0];
  const float4 v1 = *(const float4*)&Opart[o0 + 2097152];
  const size_t mi0 = ((size_t)b * 8 + h) * 1024 + i;
  const float m0 = Mm[mi0], m1 = Mm[mi0 + 32768];
  const float l0 = Ll[mi0], l1 = Ll[mi0 + 32768];
  const float M = fmaxf(m0, m1);
  const float e0 = __expf(m0 - M), e1 = __expf(m1 - M);
  const float inv = 1.0f / (l0 * e0 + l1 * e1);
  ushort4 o;
  o.x = f2bf((v0.x * e0 + v1.x * e1) * inv);
  o.y = f2bf((v0.y * e0 + v1.y * e1) * inv);
  o.z = f2bf((v0.z * e0 + v1.z * e1) * inv);
  o.w = f2bf((v0.w * e0 + v1.w * e1) * inv);
  *(ushort4*)&Ow[o0] = o;
}

}  // namespace

extern "C" void kernel_launch(void* const* d_in, const int* in_sizes, int n_in,
                              void* d_out, int out_size, void* d_ws,
                              size_t ws_size, hipStream_t stream) {
  const float* ndata = (const float*)d_in[0];
  const float* bias = (const float*)d_in[1];
  const void* mask = d_in[2];
  const float* Wq = (const float*)d_in[3];
  const float* bq = (const float*)d_in[4];
  const float* Wk = (const float*)d_in[5];
  const float* bk = (const float*)d_in[6];
  const float* Wv = (const float*)d_in[7];
  const float* bvp = (const float*)d_in[8];
  const float* Wo = (const float*)d_in[9];
  const float* bo = (const float*)d_in[10];
  float* out = (float*)d_out;

  u16* A16 = (u16*)d_ws;
  u16* W16 = A16 + 2097152;
  u16* Q16 = W16 + 1048576;
  u16* KF = Q16 + 2097152;
  u16* VF = KF + 2097152;
  u16* Ow = VF + 2097152;
  float* Opart = (float*)(Ow + 2097152);  // 2 x 2097152 f32
  float* Mm = Opart + 4194304;            // 65536
  float* Ll = Mm + 65536;                 // 65536
  u8* mask_ws = (u8*)(Ll + 65536);        // 33554432 B
  int* flag = (int*)(mask_ws + 33554432);

  detect_mask_kernel<<<1, 256, 0, stream>>>((const unsigned char*)mask, flag);
  canon_mask<<<4096, 256, 0, stream>>>((const int*)mask, flag, mask_ws);
  convert_kernel<<<3072, 256, 0, stream>>>(ndata, Wq, Wk, Wv, Wo, A16, W16);
  gemm_nt<0><<<dim3(32, 24), 256, 0, stream>>>(A16, W16, bq, bk, bvp, Q16, KF,
                                               VF, nullptr, nullptr);
  attn_fused5<<<512, 512, 0, stream>>>(Q16, KF, VF, bias, (const u8*)mask,
                                       mask_ws, flag, Opart, Mm, Ll);
  combine_halves<<<2048, 256, 0, stream>>>(Opart, Mm, Ll, Ow);
  gemm_nt<1><<<dim3(32, 8), 256, 0, stream>>>(Ow, W16, nullptr, nullptr,
                                              nullptr, nullptr, nullptr,
                                              nullptr, bo, out);
}